// Round 1
// baseline (1272.539 us; speedup 1.0000x reference)
//
#include <hip/hip_runtime.h>

// ConvLSTM on MI355X.
// Design:
//  - xpose_kernel: (B,T,C,S) f32 -> xT[b][s][t*C+c] bf16 in d_ws (67MB), tiled LDS transpose.
//  - convlstm_kernel: 32 blocks (one per batch), 512 threads (8 waves), full S=256 recurrence.
//    Per step: Z=[x_s;h] in LDS (130 rows with t-halo, 104-padded channels),
//    conv as MFMA bf16 16x16x32 (M=gate channels, N=t, K=96ch x 3 taps),
//    weights resident in VGPRs (36 frags/wave), wave owns all 4 gates for its 16 h-rows
//    -> gates fully in-register, c-state in registers, h -> LDS bf16,
//    fused output dot with Wl + sigmoid per step.

#define Bb 32
#define Tt 128
#define Cc 32
#define Ss 256
#define Hh 64

typedef __bf16 bf16x8 __attribute__((ext_vector_type(8)));
typedef short  short8 __attribute__((ext_vector_type(8)));
typedef float  f32x4  __attribute__((ext_vector_type(4)));
typedef unsigned short u16;
typedef unsigned int   u32;

__device__ __forceinline__ u16 f2bf(float f) {
    u32 u = __float_as_uint(f);
    u = (u + 0x7FFFu + ((u >> 16) & 1u)) >> 16;  // RNE
    return (u16)u;
}
__device__ __forceinline__ float fsig(float x) {
    float e = __expf(-x);
    return __builtin_amdgcn_rcpf(1.0f + e);
}
__device__ __forceinline__ float ftanh_(float x) {
    float e = __expf(2.0f * x);
    return 1.0f - 2.0f * __builtin_amdgcn_rcpf(e + 1.0f);
}

// ---------------- transpose: x (B,T,C,S) f32 -> xT (B,S,T*C) bf16 ----------------
__global__ __launch_bounds__(256) void xpose_kernel(const float* __restrict__ x,
                                                    u16* __restrict__ xT) {
    __shared__ u16 tile[64][130];  // [s][tc], pad 2 to break bank stride
    const int tc0 = blockIdx.x * 128;
    const int s0  = blockIdx.y * 64;
    const int b   = blockIdx.z;
    const int tid = threadIdx.x;
    const float* xb = x + (size_t)b * (Tt * Cc * Ss);
#pragma unroll
    for (int i = 0; i < 32; ++i) {
        const int tcr = (tid >> 6) + 4 * i;   // 0..127
        const int sr  = tid & 63;             // coalesced over s
        tile[sr][tcr] = f2bf(xb[(size_t)(tc0 + tcr) * Ss + s0 + sr]);
    }
    __syncthreads();
    u32* xTo = (u32*)(xT + (size_t)b * (Ss * Tt * Cc));
#pragma unroll
    for (int j = 0; j < 16; ++j) {
        const int sw = (tid >> 6) + 4 * j;    // 0..63
        const int tw = (tid & 63) * 2;        // coalesced over tc (pairs)
        xTo[(((size_t)(s0 + sw)) * (Tt * Cc) + tc0 + tw) >> 1] = *(const u32*)&tile[sw][tw];
    }
}

// ---------------- recurrent kernel: one block per batch ----------------
__global__ __launch_bounds__(512, 2) void convlstm_kernel(
    const float* __restrict__ Wc, const float* __restrict__ bc,
    const float* __restrict__ Wl, const float* __restrict__ bl,
    const u16* __restrict__ xT, float* __restrict__ out) {

    // Z buffers: rows 0..129 = t -1..128 (halo rows stay zero), cols 0..31 x, 32..95 h, 96..103 pad
    __shared__ u16  zbuf[2][130][104];
    __shared__ float red[8][16];
    __shared__ float bcl[256];

    const int b    = blockIdx.x;
    const int tid  = threadIdx.x;
    const int w    = tid >> 6;     // wave 0..7
    const int lane = tid & 63;
    const int l15  = lane & 15;
    const int q    = lane >> 4;    // lane quarter
    const int ht   = w >> 1;       // h-tile 0..3 (16 h rows each)
    const int th   = w & 1;        // t-half 0..1 (64 cols each)

    // zero LDS Z buffers (halos must be zero; h region = h(-1) = 0)
    {
        u32* z32 = (u32*)&zbuf[0][0][0];
        for (int i = tid; i < (2 * 130 * 104) / 2; i += 512) z32[i] = 0;
    }
    if (tid < 256) bcl[tid] = bc[tid];

    // weight fragments, resident in registers: afr[gate][tap][kslice]
    // A[m][k]: m = gc row (lane&15 within 16-row tile), k-slot j -> channel 32*ks + 8*q + j.
    // (A and B use the SAME slot->k mapping, so the result is invariant to HW k wiring.)
    bf16x8 afr[4][3][3];
#pragma unroll
    for (int g = 0; g < 4; ++g) {
#pragma unroll
        for (int k = 0; k < 3; ++k) {
#pragma unroll
            for (int ks = 0; ks < 3; ++ks) {
                const int gc = 64 * g + 16 * ht + l15;
                short8 t;
#pragma unroll
                for (int j = 0; j < 8; ++j) {
                    const int c = 32 * ks + 8 * q + j;
                    t[j] = (short)f2bf(Wc[gc * 288 + c * 3 + k]);
                }
                afr[g][k][ks] = __builtin_bit_cast(bf16x8, t);
            }
        }
    }

    float wlv[4];
#pragma unroll
    for (int nj = 0; nj < 4; ++nj) wlv[nj] = Wl[64 * th + 16 * nj + l15];
    const float bl0 = bl[0];

    float cst[16];  // c-state: [nj][r] for this lane's cells
#pragma unroll
    for (int i = 0; i < 16; ++i) cst[i] = 0.0f;

    // x staging: thread -> (t = tid>>2, c0 = (tid&3)*8), 8 bf16 = 16B
    const int xt = tid >> 2;
    const int xc = (tid & 3) * 8;
    const u16* xTb = xT + (size_t)b * (Ss * Tt * Cc);

    // prime x(0) into buffer 0
    {
        uint4 xv0 = *(const uint4*)(xTb + 0 + xt * 32 + xc);
        __syncthreads();  // zbuf zero + bcl complete
        *(uint4*)&zbuf[0][1 + xt][xc] = xv0;
        __syncthreads();  // x(0) visible
    }

    float* outb = out + (size_t)b * (Ss * Hh);
    int p = 0;

    for (int s = 0; s < Ss; ++s) {
        // prefetch x(s+1) (issue early; written to LDS after compute)
        uint4 xv;
        const bool havex = (s + 1) < Ss;
        if (havex) xv = *(const uint4*)(xTb + (size_t)(s + 1) * (Tt * Cc) + xt * 32 + xc);

        // wave0: emit output for step s-1 (reads red written before last barrier)
        if (tid < 64 && s > 0) {
            float v = red[(tid >> 4) * 2][tid & 15] + red[(tid >> 4) * 2 + 1][tid & 15] + bl0;
            outb[(size_t)(s - 1) * Hh + tid] = fsig(v);
        }
        __syncthreads();  // barrier A: protects red before it is rewritten below

        const u16 (*zb)[104] = zbuf[p];
        u16 (*zn)[104] = zbuf[p ^ 1];

        float partial[4] = {0.f, 0.f, 0.f, 0.f};

#pragma unroll
        for (int half = 0; half < 2; ++half) {
            f32x4 acc[4][2];
#pragma unroll
            for (int g = 0; g < 4; ++g)
#pragma unroll
                for (int njl = 0; njl < 2; ++njl)
                    acc[g][njl] = (f32x4){0.f, 0.f, 0.f, 0.f};

#pragma unroll
            for (int njl = 0; njl < 2; ++njl) {
                const int nj = half * 2 + njl;
                const int tb = 64 * th + 16 * nj + l15;  // LDS row = t + tap (row0 = t=-1)
#pragma unroll
                for (int k = 0; k < 3; ++k) {
#pragma unroll
                    for (int ks = 0; ks < 3; ++ks) {
                        bf16x8 bfr = *(const bf16x8*)&zb[tb + k][32 * ks + 8 * q];
                        acc[0][njl] = __builtin_amdgcn_mfma_f32_16x16x32_bf16(afr[0][k][ks], bfr, acc[0][njl], 0, 0, 0);
                        acc[1][njl] = __builtin_amdgcn_mfma_f32_16x16x32_bf16(afr[1][k][ks], bfr, acc[1][njl], 0, 0, 0);
                        acc[2][njl] = __builtin_amdgcn_mfma_f32_16x16x32_bf16(afr[2][k][ks], bfr, acc[2][njl], 0, 0, 0);
                        acc[3][njl] = __builtin_amdgcn_mfma_f32_16x16x32_bf16(afr[3][k][ks], bfr, acc[3][njl], 0, 0, 0);
                    }
                }
            }

            // gates for this half, fully in-register (D layout: col=lane&15, row=4*q+reg)
#pragma unroll
            for (int njl = 0; njl < 2; ++njl) {
                const int nj = half * 2 + njl;
                u16 hp[4];
#pragma unroll
                for (int r = 0; r < 4; ++r) {
                    const int hl = 4 * q + r;
                    const float ci  = acc[0][njl][r] + bcl[0   + 16 * ht + hl];
                    const float cf  = acc[1][njl][r] + bcl[64  + 16 * ht + hl];
                    const float cop = acc[2][njl][r] + bcl[128 + 16 * ht + hl];
                    const float cg  = acc[3][njl][r] + bcl[192 + 16 * ht + hl];
                    const float ig = fsig(ci);
                    const float fg = fsig(cf);
                    const float og = fsig(cop);
                    const float gg = ftanh_(cg);
                    const float cv = fg * cst[nj * 4 + r] + ig * gg;
                    cst[nj * 4 + r] = cv;
                    const float hv = og * ftanh_(cv);
                    partial[r] += hv * wlv[nj];
                    hp[r] = f2bf(hv);
                }
                uint2 hw;
                hw.x = (u32)hp[0] | ((u32)hp[1] << 16);
                hw.y = (u32)hp[2] | ((u32)hp[3] << 16);
                // h channel = 16*ht + 4*q + r  -> Z col 32 + that (8B aligned)
                *(uint2*)&zn[1 + 64 * th + 16 * nj + l15][32 + 16 * ht + 4 * q] = hw;
            }
        }

        // write prefetched x(s+1)
        if (havex) *(uint4*)&zn[1 + xt][xc] = xv;

        // reduce output partials over the 16 t-lanes of each quarter
#pragma unroll
        for (int r = 0; r < 4; ++r) {
#pragma unroll
            for (int off = 1; off <= 8; off <<= 1)
                partial[r] += __shfl_xor(partial[r], off, 64);
        }
        if (l15 == 0) {
#pragma unroll
            for (int r = 0; r < 4; ++r) red[w][4 * q + r] = partial[r];
        }
        __syncthreads();  // barrier B: h(s), x(s+1), red visible
        p ^= 1;
    }

    // final output for s = Ss-1
    if (tid < 64) {
        float v = red[(tid >> 4) * 2][tid & 15] + red[(tid >> 4) * 2 + 1][tid & 15] + bl0;
        outb[(size_t)(Ss - 1) * Hh + tid] = fsig(v);
    }
}

extern "C" void kernel_launch(void* const* d_in, const int* in_sizes, int n_in,
                              void* d_out, int out_size, void* d_ws, size_t ws_size,
                              hipStream_t stream) {
    const float* x  = (const float*)d_in[0];
    const float* Wc = (const float*)d_in[1];
    const float* bc = (const float*)d_in[2];
    const float* Wl = (const float*)d_in[3];
    const float* bl = (const float*)d_in[4];
    float* out = (float*)d_out;
    u16*   xT  = (u16*)d_ws;  // needs 32*256*4096*2 = 64 MiB

    dim3 tgrid(Tt * Cc / 128, Ss / 64, Bb);  // (32, 4, 32)
    xpose_kernel<<<tgrid, 256, 0, stream>>>(x, xT);
    convlstm_kernel<<<Bb, 512, 0, stream>>>(Wc, bc, Wl, bl, xT, out);
}